// Round 1
// baseline (3324.308 us; speedup 1.0000x reference)
//
#include <hip/hip_runtime.h>
#include <math.h>

#define PP 196608
#define NK 8
#define BM 64

#define O_RGBALL 0
#define O_SIGALL 589824
#define O_RGB    786432
#define O_SIG    5505024

// Dense partial-accumulate: acc[jj] += W[(jbase+jj)*LDW + COFF + i] * sIn[i][m]
template<int INDIM, int LDW, int COFF, int NJ>
__device__ __forceinline__ void denseN(const float (*sIn)[64], const float* __restrict__ W,
                                       float* acc, int jbase, int m)
{
    #pragma unroll 4
    for (int i = 0; i < INDIM; ++i) {
        float a = sIn[i][m];
        #pragma unroll
        for (int jj = 0; jj < NJ; ++jj)
            acc[jj] = fmaf(W[(jbase + jj) * LDW + COFF + i], a, acc[jj]);
    }
}

template<int NJ, bool RELU>
__device__ __forceinline__ void storeN(float (*sOut)[64], const float* acc, int jbase, int m)
{
    #pragma unroll
    for (int jj = 0; jj < NJ; ++jj) {
        float v = acc[jj];
        sOut[jbase + jj][m] = RELU ? fmaxf(v, 0.f) : v;
    }
}

__global__ __launch_bounds__(256, 3) void decoder_kernel(
    const float* __restrict__ coor,      // (P,3)
    const float* __restrict__ view,      // (N,3)
    const float* __restrict__ slots,     // (1,K,64)
    const float* __restrict__ dens,      // (K,P)
    const float* __restrict__ act_shift, // (1,)
    const float* __restrict__ Wb0, const float* __restrict__ bb0,
    const float* __restrict__ Wb1, const float* __restrict__ bb1,
    const float* __restrict__ Wb2, const float* __restrict__ bb2,
    const float* __restrict__ Wa0, const float* __restrict__ ba0,
    const float* __restrict__ Wa1, const float* __restrict__ ba1,
    const float* __restrict__ Wa2, const float* __restrict__ ba2,
    const float* __restrict__ Wl,  const float* __restrict__ bl,
    const float* __restrict__ Wv,  const float* __restrict__ bv,
    const float* __restrict__ Wc0, const float* __restrict__ bc0,
    const float* __restrict__ Wc1, const float* __restrict__ bc1,
    const int*   __restrict__ ray_id,
    float* __restrict__ out)
{
    __shared__ float sA[64][64];      // act ping
    __shared__ float sB[64][64];      // act pong
    __shared__ float sEmb[33][64];    // coor pos-emb, transposed [feat][m]
    __shared__ float sVemb[21][64];   // view pos-emb, transposed
    __shared__ float sBB0[NK][64];    // slot-folded bias for Wb0
    __shared__ float sBA0[NK][64];    // slot-folded bias for Wa0
    __shared__ float sW[NK][64];      // mask weight m_k / (sum + 1e-5)

    const int tid = threadIdx.x;
    const int m = tid & 63;
    const int g = __builtin_amdgcn_readfirstlane(tid >> 6); // wave id 0..3 (SGPR)
    const int p0 = blockIdx.x * BM;
    const int p = p0 + m;

    if (tid < 64) {
        // ---- per-point embeddings, masks, sigma outputs ----
        float c0 = coor[p * 3 + 0], c1 = coor[p * 3 + 1], c2 = coor[p * 3 + 2];
        sEmb[0][m] = c0; sEmb[1][m] = c1; sEmb[2][m] = c2;
        #pragma unroll
        for (int f = 0; f < 5; ++f) {
            float fr = (float)(1 << f);
            sEmb[3 + f * 6 + 0][m] = sinf(c0 * fr);
            sEmb[3 + f * 6 + 1][m] = sinf(c1 * fr);
            sEmb[3 + f * 6 + 2][m] = sinf(c2 * fr);
            sEmb[3 + f * 6 + 3][m] = cosf(c0 * fr);
            sEmb[3 + f * 6 + 4][m] = cosf(c1 * fr);
            sEmb[3 + f * 6 + 5][m] = cosf(c2 * fr);
        }
        int rid = ray_id[p];
        float v0 = view[rid * 3 + 0], v1 = view[rid * 3 + 1], v2 = view[rid * 3 + 2];
        sVemb[0][m] = v0; sVemb[1][m] = v1; sVemb[2][m] = v2;
        #pragma unroll
        for (int f = 0; f < 3; ++f) {
            float fr = (float)(1 << f);
            sVemb[3 + f * 6 + 0][m] = sinf(v0 * fr);
            sVemb[3 + f * 6 + 1][m] = sinf(v1 * fr);
            sVemb[3 + f * 6 + 2][m] = sinf(v2 * fr);
            sVemb[3 + f * 6 + 3][m] = cosf(v0 * fr);
            sVemb[3 + f * 6 + 4][m] = cosf(v1 * fr);
            sVemb[3 + f * 6 + 5][m] = cosf(v2 * fr);
        }
        float shift = act_shift[0];
        float mk[NK];
        float msum = 0.f;
        #pragma unroll
        for (int kk = 0; kk < NK; ++kk) {
            float d = dens[kk * PP + p] + shift;
            float sp = fmaxf(d, 0.f) + log1pf(expf(-fabsf(d)));  // softplus, stable
            mk[kk] = sp; msum += sp;
            out[O_SIG + kk * PP + p] = sp;
        }
        float inv = 1.f / (msum + 1e-5f);
        float sig = 0.f;
        #pragma unroll
        for (int kk = 0; kk < NK; ++kk) {
            sig += mk[kk] * mk[kk];
            sW[kk][m] = mk[kk] * inv;
        }
        out[O_SIGALL + p] = sig * inv;
    } else {
        // ---- fold slots into first-layer biases: 1024 dot-64 jobs ----
        for (int t = tid - 64; t < 1024; t += 192) {
            int sel = t >> 9;
            int kk = (t >> 6) & 7;
            int j = t & 63;
            const float* sl = slots + kk * 64;
            if (sel == 0) {
                float a = bb0[j];
                const float* w = Wb0 + j * 97 + 33;
                for (int i = 0; i < 64; ++i) a = fmaf(w[i], sl[i], a);
                sBB0[kk][j] = a;
            } else {
                float a = ba0[j];
                const float* w = Wa0 + j * 161 + 33;
                for (int i = 0; i < 64; ++i) a = fmaf(w[i], sl[i], a);
                sBA0[kk][j] = a;
            }
        }
    }
    __syncthreads();

    float rgbAll = 0.f;

    #pragma unroll 1
    for (int kk = 0; kk < NK; ++kk) {
        const int jb16 = g * 16;
        // b0: sEmb(33) -> sB
        {
            float acc[16];
            #pragma unroll
            for (int jj = 0; jj < 16; ++jj) acc[jj] = sBB0[kk][jb16 + jj];
            denseN<33, 97, 0, 16>(sEmb, Wb0, acc, jb16, m);
            storeN<16, true>(sB, acc, jb16, m);
        }
        __syncthreads();
        // b1: sB -> sA
        {
            float acc[16];
            #pragma unroll
            for (int jj = 0; jj < 16; ++jj) acc[jj] = bb1[jb16 + jj];
            denseN<64, 64, 0, 16>(sB, Wb1, acc, jb16, m);
            storeN<16, true>(sA, acc, jb16, m);
        }
        __syncthreads();
        // b2: sA -> sB
        {
            float acc[16];
            #pragma unroll
            for (int jj = 0; jj < 16; ++jj) acc[jj] = bb2[jb16 + jj];
            denseN<64, 64, 0, 16>(sA, Wb2, acc, jb16, m);
            storeN<16, true>(sB, acc, jb16, m);
        }
        __syncthreads();
        // a0 (skip concat): sEmb(33 @ col 0) + sB(64 @ col 97) -> sA
        {
            float acc[16];
            #pragma unroll
            for (int jj = 0; jj < 16; ++jj) acc[jj] = sBA0[kk][jb16 + jj];
            denseN<33, 161, 0, 16>(sEmb, Wa0, acc, jb16, m);
            denseN<64, 161, 97, 16>(sB, Wa0, acc, jb16, m);
            storeN<16, true>(sA, acc, jb16, m);
        }
        __syncthreads();
        // a1: sA -> sB
        {
            float acc[16];
            #pragma unroll
            for (int jj = 0; jj < 16; ++jj) acc[jj] = ba1[jb16 + jj];
            denseN<64, 64, 0, 16>(sA, Wa1, acc, jb16, m);
            storeN<16, true>(sB, acc, jb16, m);
        }
        __syncthreads();
        // a2: sB -> sA
        {
            float acc[16];
            #pragma unroll
            for (int jj = 0; jj < 16; ++jj) acc[jj] = ba2[jb16 + jj];
            denseN<64, 64, 0, 16>(sB, Wa2, acc, jb16, m);
            storeN<16, true>(sA, acc, jb16, m);
        }
        __syncthreads();
        // latent (no relu): sA -> sB
        {
            float acc[16];
            #pragma unroll
            for (int jj = 0; jj < 16; ++jj) acc[jj] = bl[jb16 + jj];
            denseN<64, 64, 0, 16>(sA, Wl, acc, jb16, m);
            storeN<16, false>(sB, acc, jb16, m);
        }
        __syncthreads();
        // views: sB(latent, 64 @ col 0) + sVemb(21 @ col 64) -> sA rows 0..31
        {
            const int jb8 = g * 8;
            float acc[8];
            #pragma unroll
            for (int jj = 0; jj < 8; ++jj) acc[jj] = bv[jb8 + jj];
            denseN<64, 85, 0, 8>(sB, Wv, acc, jb8, m);
            denseN<21, 85, 64, 8>(sVemb, Wv, acc, jb8, m);
            storeN<8, true>(sA, acc, jb8, m);
        }
        __syncthreads();
        // color0: sA rows 0..31 -> sB rows 0..15
        {
            const int jb4 = g * 4;
            float acc[4];
            #pragma unroll
            for (int jj = 0; jj < 4; ++jj) acc[jj] = bc0[jb4 + jj];
            denseN<32, 32, 0, 4>(sA, Wc0, acc, jb4, m);
            storeN<4, true>(sB, acc, jb4, m);
        }
        __syncthreads();
        // color1 + tanh + mask-weighted accumulation
        if (g < 3) {
            float acc = bc1[g];
            #pragma unroll
            for (int i = 0; i < 16; ++i) acc = fmaf(Wc1[g * 16 + i], sB[i][m], acc);
            float rgb = (tanhf(acc) + 1.f) * 0.5f;
            out[O_RGB + (kk * PP + p) * 3 + g] = rgb;
            rgbAll = fmaf(rgb, sW[kk][m], rgbAll);
        }
        __syncthreads();  // protect sB before next-k b0 writes
    }

    if (g < 3) out[(p)*3 + g] = rgbAll;
}

extern "C" void kernel_launch(void* const* d_in, const int* in_sizes, int n_in,
                              void* d_out, int out_size, void* d_ws, size_t ws_size,
                              hipStream_t stream) {
    const float* coor  = (const float*)d_in[0];
    const float* view  = (const float*)d_in[1];
    const float* slots = (const float*)d_in[2];
    const float* dens  = (const float*)d_in[3];
    const float* shf   = (const float*)d_in[4];
    const float* Wb0 = (const float*)d_in[5];  const float* bb0 = (const float*)d_in[6];
    const float* Wb1 = (const float*)d_in[7];  const float* bb1 = (const float*)d_in[8];
    const float* Wb2 = (const float*)d_in[9];  const float* bb2 = (const float*)d_in[10];
    const float* Wa0 = (const float*)d_in[11]; const float* ba0 = (const float*)d_in[12];
    const float* Wa1 = (const float*)d_in[13]; const float* ba1 = (const float*)d_in[14];
    const float* Wa2 = (const float*)d_in[15]; const float* ba2 = (const float*)d_in[16];
    const float* Wl  = (const float*)d_in[17]; const float* bl  = (const float*)d_in[18];
    const float* Wv  = (const float*)d_in[19]; const float* bv  = (const float*)d_in[20];
    const float* Wc0 = (const float*)d_in[21]; const float* bc0 = (const float*)d_in[22];
    const float* Wc1 = (const float*)d_in[23]; const float* bc1 = (const float*)d_in[24];
    const int*   ray = (const int*)d_in[25];
    float* out = (float*)d_out;

    decoder_kernel<<<dim3(PP / BM), dim3(256), 0, stream>>>(
        coor, view, slots, dens, shf,
        Wb0, bb0, Wb1, bb1, Wb2, bb2,
        Wa0, ba0, Wa1, ba1, Wa2, ba2,
        Wl, bl, Wv, bv, Wc0, bc0, Wc1, bc1,
        ray, out);
}

// Round 5
// 535.923 us; speedup vs baseline: 6.2030x; 6.2030x over previous
//
#include <hip/hip_runtime.h>
#include <math.h>

#define PP 196608
#define NK 8

#define O_SIGALL 589824
#define O_RGB    786432
#define O_SIG    5505024

typedef __attribute__((ext_vector_type(8))) short short8;
typedef __attribute__((ext_vector_type(4))) float f32x4;

// ---- workspace byte offsets ----
#define OW_B0 0
#define OW_B1 8192
#define OW_B2 16384
#define OW_A0 24576
#define OW_A1 40960
#define OW_A2 49152
#define OW_L  57344
#define OW_V  65536
#define OW_C0 71680
#define OW_C1 72704
#define OB_B0 73728
#define OB_A0 75776
#define OB_B1 77824
#define OB_B2 78080
#define OB_A1 78336
#define OB_A2 78592
#define OB_L  78848
#define OB_V  79104
#define OB_C0 79232
#define OB_C1 79296

// float -> bf16 bits, round-nearest-even (no __bf16 type dependence)
__device__ __forceinline__ short bfr(float f) {
    unsigned u = __builtin_bit_cast(unsigned, f);
    unsigned r = (u + 0x7FFFu + ((u >> 16) & 1u)) >> 16;
    return (short)r;
}

// stored col p (0..31 within 32-block) -> logical col offset
__device__ __forceinline__ int tau(int p) {
    return 16 * ((p >> 2) & 1) + 4 * (p >> 3) + (p & 3);
}

#define MFMA(a, b, c) __builtin_amdgcn_mfma_f32_16x16x32_bf16(a, b, c, 0, 0, 0)

// ================= prep kernel =================
__global__ void prep_kernel(
    const float* __restrict__ slots,
    const float* __restrict__ Wb0, const float* __restrict__ bb0,
    const float* __restrict__ Wb1, const float* __restrict__ bb1,
    const float* __restrict__ Wb2, const float* __restrict__ bb2,
    const float* __restrict__ Wa0, const float* __restrict__ ba0,
    const float* __restrict__ Wa1, const float* __restrict__ ba1,
    const float* __restrict__ Wa2, const float* __restrict__ ba2,
    const float* __restrict__ Wl,  const float* __restrict__ bl,
    const float* __restrict__ Wv,  const float* __restrict__ bv,
    const float* __restrict__ Wc0, const float* __restrict__ bc0,
    const float* __restrict__ Wc1, const float* __restrict__ bc1,
    char* __restrict__ ws)
{
    short* wsS = (short*)ws;
    float* wsF = (float*)ws;
    const int tid = threadIdx.x;

    // b0: [64][64], real cols 33 (emb part of Wb0)
    for (int idx = tid; idx < 64 * 64; idx += 256) {
        int j = idx >> 6, C = idx & 63;
        int lc = (C & ~31) + tau(C & 31);
        wsS[OW_B0 / 2 + idx] = bfr(lc < 33 ? Wb0[j * 97 + lc] : 0.f);
    }
    // b1,b2,a1,a2,lat: [64][64] full
    for (int idx = tid; idx < 64 * 64; idx += 256) {
        int j = idx >> 6, C = idx & 63;
        int lc = (C & ~31) + tau(C & 31);
        float vb1 = Wb1[j * 64 + lc], vb2 = Wb2[j * 64 + lc];
        float va1 = Wa1[j * 64 + lc], va2 = Wa2[j * 64 + lc];
        float vl  = Wl [j * 64 + lc];
        wsS[OW_B1 / 2 + idx] = bfr(vb1);
        wsS[OW_B2 / 2 + idx] = bfr(vb2);
        wsS[OW_A1 / 2 + idx] = bfr(va1);
        wsS[OW_A2 / 2 + idx] = bfr(va2);
        wsS[OW_L  / 2 + idx] = bfr(vl);
    }
    // a0: [64][128]; cols 0..32 = emb part, 64..127 = skip part (src cols 97..160)
    for (int idx = tid; idx < 64 * 128; idx += 256) {
        int j = idx >> 7, C = idx & 127;
        int lc = (C & ~31) + tau(C & 31);
        float v = 0.f;
        if (lc < 33) v = Wa0[j * 161 + lc];
        else if (lc >= 64) v = Wa0[j * 161 + 33 + lc];  // 97 + (lc-64)
        wsS[OW_A0 / 2 + idx] = bfr(v);
    }
    // views: [32][96]; cols 0..63 latent, 64..84 view-emb
    for (int idx = tid; idx < 32 * 96; idx += 256) {
        int j = idx / 96, C = idx % 96;
        int lc = (C & ~31) + tau(C & 31);
        wsS[OW_V / 2 + idx] = bfr(lc < 85 ? Wv[j * 85 + lc] : 0.f);
    }
    // c0: [16][32]
    for (int idx = tid; idx < 16 * 32; idx += 256) {
        int j = idx >> 5, C = idx & 31;
        int lc = tau(C);
        wsS[OW_C0 / 2 + idx] = bfr(Wc0[j * 32 + lc]);
    }
    // c1: [16][32]; 3 real rows, 16 real cols
    for (int idx = tid; idx < 16 * 32; idx += 256) {
        int j = idx >> 5, C = idx & 31;
        int lc = tau(C);
        wsS[OW_C1 / 2 + idx] = bfr((j < 3 && lc < 16) ? Wc1[j * 16 + lc] : 0.f);
    }
    // slot-folded biases: b0 / a0 (slot features at src cols 33..96)
    for (int idx = tid; idx < 512; idx += 256) {
        int k = idx >> 6, j = idx & 63;
        const float* sl = slots + k * 64;
        float a = bb0[j];
        const float* w0 = Wb0 + j * 97 + 33;
        for (int i = 0; i < 64; ++i) a = fmaf(w0[i], sl[i], a);
        wsF[OB_B0 / 4 + idx] = a;
        float b = ba0[j];
        const float* w1 = Wa0 + j * 161 + 33;
        for (int i = 0; i < 64; ++i) b = fmaf(w1[i], sl[i], b);
        wsF[OB_A0 / 4 + idx] = b;
    }
    // plain biases
    for (int idx = tid; idx < 64; idx += 256) {
        wsF[OB_B1 / 4 + idx] = bb1[idx];
        wsF[OB_B2 / 4 + idx] = bb2[idx];
        wsF[OB_A1 / 4 + idx] = ba1[idx];
        wsF[OB_A2 / 4 + idx] = ba2[idx];
        wsF[OB_L  / 4 + idx] = bl[idx];
        if (idx < 32) wsF[OB_V / 4 + idx] = bv[idx];
        if (idx < 16) wsF[OB_C0 / 4 + idx] = bc0[idx];
        if (idx < 16) wsF[OB_C1 / 4 + idx] = (idx < 3) ? bc1[idx] : 0.f;
    }
}

// ================= main kernel helpers =================
template<int NT, int NS, int KP>
__device__ __forceinline__ void loadA(const short* W, int l15, int g8, short8 (&A)[NT][NS]) {
    #pragma unroll
    for (int t = 0; t < NT; ++t)
        #pragma unroll
        for (int s = 0; s < NS; ++s)
            A[t][s] = *(const short8*)(W + (16 * t + l15) * KP + 32 * s + g8);
}

template<bool RELU>
__device__ __forceinline__ void pack4(const f32x4 (&c)[4], short8 (&o)[2]) {
    #pragma unroll
    for (int s = 0; s < 2; ++s) {
        short8 f;
        #pragma unroll
        for (int i = 0; i < 8; ++i) {
            float v = c[2 * s + (i >> 2)][i & 3];
            if (RELU) v = fmaxf(v, 0.f);
            f[i] = bfr(v);
        }
        o[s] = f;
    }
}

__device__ __forceinline__ void layer64(const short8 (&A)[4][2], const short8 (&B)[2],
                                        const float* bias, int g4, f32x4 (&c)[4]) {
    #pragma unroll
    for (int t = 0; t < 4; ++t) c[t] = *(const f32x4*)(bias + 16 * t + g4);
    #pragma unroll
    for (int s = 0; s < 2; ++s)
        #pragma unroll
        for (int t = 0; t < 4; ++t)
            c[t] = MFMA(A[t][s], B[s], c[t]);
}

// ================= main kernel =================
__global__ __launch_bounds__(256, 2) void decoder_kernel(
    const float* __restrict__ coor,
    const float* __restrict__ view,
    const float* __restrict__ dens,
    const float* __restrict__ act_shift,
    const int*   __restrict__ ray_id,
    const char*  __restrict__ ws,
    float* __restrict__ out)
{
    const short* wsS = (const short*)ws;
    const float* wsF = (const float*)ws;
    const int tid = threadIdx.x;
    const int l   = tid & 63;
    const int l15 = l & 15;
    const int g   = (l >> 4) & 3;
    const int g8  = g * 8;
    const int g4  = g * 4;
    const int p   = blockIdx.x * 64 + (tid >> 6) * 16 + l15;

    // ---- positional embedding (48-padded) ----
    float e[64];
    #pragma unroll
    for (int i = 0; i < 64; ++i) e[i] = 0.f;
    {
        float c0 = coor[p * 3 + 0], c1 = coor[p * 3 + 1], c2 = coor[p * 3 + 2];
        e[0] = c0; e[1] = c1; e[2] = c2;
        #pragma unroll
        for (int f = 0; f < 5; ++f) {
            float fr = (float)(1 << f);
            e[3 + 6 * f + 0] = sinf(c0 * fr);
            e[3 + 6 * f + 1] = sinf(c1 * fr);
            e[3 + 6 * f + 2] = sinf(c2 * fr);
            e[3 + 6 * f + 3] = cosf(c0 * fr);
            e[3 + 6 * f + 4] = cosf(c1 * fr);
            e[3 + 6 * f + 5] = cosf(c2 * fr);
        }
    }
    short8 embB[2];
    #pragma unroll
    for (int s = 0; s < 2; ++s) {
        short8 f;
        #pragma unroll
        for (int i = 0; i < 8; ++i) {
            int base = 32 * s + 16 * (i >> 2) + (i & 3);
            float v0 = e[base], v1 = e[base + 4], v2 = e[base + 8], v3 = e[base + 12];
            float a = (g & 1) ? v1 : v0;
            float b = (g & 1) ? v3 : v2;
            f[i] = bfr((g & 2) ? b : a);
        }
        embB[s] = f;
    }
    // ---- view embedding (32-padded) ----
    float ve[32];
    #pragma unroll
    for (int i = 0; i < 32; ++i) ve[i] = 0.f;
    {
        int rid = ray_id[p];
        float v0 = view[rid * 3 + 0], v1 = view[rid * 3 + 1], v2 = view[rid * 3 + 2];
        ve[0] = v0; ve[1] = v1; ve[2] = v2;
        #pragma unroll
        for (int f = 0; f < 3; ++f) {
            float fr = (float)(1 << f);
            ve[3 + 6 * f + 0] = sinf(v0 * fr);
            ve[3 + 6 * f + 1] = sinf(v1 * fr);
            ve[3 + 6 * f + 2] = sinf(v2 * fr);
            ve[3 + 6 * f + 3] = cosf(v0 * fr);
            ve[3 + 6 * f + 4] = cosf(v1 * fr);
            ve[3 + 6 * f + 5] = cosf(v2 * fr);
        }
    }
    short8 vembB;
    #pragma unroll
    for (int i = 0; i < 8; ++i) {
        int base = 16 * (i >> 2) + (i & 3);
        float v0 = ve[base], v1 = ve[base + 4], v2 = ve[base + 8], v3 = ve[base + 12];
        float a = (g & 1) ? v1 : v0;
        float b = (g & 1) ? v3 : v2;
        vembB[i] = bfr((g & 2) ? b : a);
    }

    // ---- masks / sigma ----
    float w[8], mk[8];
    float msum = 0.f;
    float shift = act_shift[0];
    #pragma unroll
    for (int k = 0; k < 8; ++k) {
        float d = dens[k * PP + p] + shift;
        float sp = fmaxf(d, 0.f) + log1pf(expf(-fabsf(d)));
        mk[k] = sp; msum += sp;
        if (l < 16) out[O_SIG + k * PP + p] = sp;
    }
    float inv = 1.f / (msum + 1e-5f);
    float mk2 = 0.f;
    #pragma unroll
    for (int k = 0; k < 8; ++k) { w[k] = mk[k] * inv; mk2 += mk[k] * mk[k]; }
    if (l < 16) out[O_SIGALL + p] = mk2 * inv;

    // ---- MLP over 8 slots, 4 at a time ----
    float rgbA0 = 0.f, rgbA1 = 0.f, rgbA2 = 0.f;
    short8 act[4][2];

    #pragma unroll 1
    for (int kq = 0; kq < 2; ++kq) {
        const float* BB0 = wsF + OB_B0 / 4 + kq * 256;
        const float* BA0 = wsF + OB_A0 / 4 + kq * 256;

        { // b0: emb -> 64
            short8 A[4][2]; loadA<4, 2, 64>(wsS + OW_B0 / 2, l15, g8, A);
            #pragma unroll
            for (int si = 0; si < 4; ++si) {
                f32x4 c[4];
                layer64(A, embB, BB0 + si * 64, g4, c);
                pack4<true>(c, act[si]);
            }
        }
        { // b1
            short8 A[4][2]; loadA<4, 2, 64>(wsS + OW_B1 / 2, l15, g8, A);
            #pragma unroll
            for (int si = 0; si < 4; ++si) {
                f32x4 c[4];
                layer64(A, act[si], wsF + OB_B1 / 4, g4, c);
                pack4<true>(c, act[si]);
            }
        }
        { // b2
            short8 A[4][2]; loadA<4, 2, 64>(wsS + OW_B2 / 2, l15, g8, A);
            #pragma unroll
            for (int si = 0; si < 4; ++si) {
                f32x4 c[4];
                layer64(A, act[si], wsF + OB_B2 / 4, g4, c);
                pack4<true>(c, act[si]);
            }
        }
        { // a0: [emb | skip] -> 64
            short8 A[4][4]; loadA<4, 4, 128>(wsS + OW_A0 / 2, l15, g8, A);
            #pragma unroll
            for (int si = 0; si < 4; ++si) {
                f32x4 c[4];
                #pragma unroll
                for (int t = 0; t < 4; ++t) c[t] = *(const f32x4*)(BA0 + si * 64 + 16 * t + g4);
                #pragma unroll
                for (int t = 0; t < 4; ++t) {
                    c[t] = MFMA(A[t][0], embB[0], c[t]);
                    c[t] = MFMA(A[t][1], embB[1], c[t]);
                    c[t] = MFMA(A[t][2], act[si][0], c[t]);
                    c[t] = MFMA(A[t][3], act[si][1], c[t]);
                }
                pack4<true>(c, act[si]);
            }
        }
        { // a1
            short8 A[4][2]; loadA<4, 2, 64>(wsS + OW_A1 / 2, l15, g8, A);
            #pragma unroll
            for (int si = 0; si < 4; ++si) {
                f32x4 c[4];
                layer64(A, act[si], wsF + OB_A1 / 4, g4, c);
                pack4<true>(c, act[si]);
            }
        }
        { // a2
            short8 A[4][2]; loadA<4, 2, 64>(wsS + OW_A2 / 2, l15, g8, A);
            #pragma unroll
            for (int si = 0; si < 4; ++si) {
                f32x4 c[4];
                layer64(A, act[si], wsF + OB_A2 / 4, g4, c);
                pack4<true>(c, act[si]);
            }
        }
        { // latent (no relu)
            short8 A[4][2]; loadA<4, 2, 64>(wsS + OW_L / 2, l15, g8, A);
            #pragma unroll
            for (int si = 0; si < 4; ++si) {
                f32x4 c[4];
                layer64(A, act[si], wsF + OB_L / 4, g4, c);
                pack4<false>(c, act[si]);
            }
        }
        { // tail: views -> c0 -> c1 -> rgb
            short8 AV[2][3];  loadA<2, 3, 96>(wsS + OW_V  / 2, l15, g8, AV);
            short8 AC0[1][1]; loadA<1, 1, 32>(wsS + OW_C0 / 2, l15, g8, AC0);
            short8 AC1[1][1]; loadA<1, 1, 32>(wsS + OW_C1 / 2, l15, g8, AC1);
            #pragma unroll
            for (int si = 0; si < 4; ++si) {
                int slot = 4 * kq + si;
                f32x4 cv[2];
                #pragma unroll
                for (int t = 0; t < 2; ++t) cv[t] = *(const f32x4*)(wsF + OB_V / 4 + 16 * t + g4);
                #pragma unroll
                for (int t = 0; t < 2; ++t) {
                    cv[t] = MFMA(AV[t][0], act[si][0], cv[t]);
                    cv[t] = MFMA(AV[t][1], act[si][1], cv[t]);
                    cv[t] = MFMA(AV[t][2], vembB, cv[t]);
                }
                short8 vB;
                #pragma unroll
                for (int i = 0; i < 8; ++i) vB[i] = bfr(fmaxf(cv[i >> 2][i & 3], 0.f));
                f32x4 cc = *(const f32x4*)(wsF + OB_C0 / 4 + g4);
                cc = MFMA(AC0[0][0], vB, cc);
                short8 cB;
                #pragma unroll
                for (int i = 0; i < 8; ++i) cB[i] = (i < 4) ? bfr(fmaxf(cc[i], 0.f)) : (short)0;
                f32x4 cf = *(const f32x4*)(wsF + OB_C1 / 4 + g4);
                cf = MFMA(AC1[0][0], cB, cf);
                float r0 = (tanhf(cf[0]) + 1.f) * 0.5f;
                float r1 = (tanhf(cf[1]) + 1.f) * 0.5f;
                float r2 = (tanhf(cf[2]) + 1.f) * 0.5f;
                float wlo = w[si], whi = w[si + 4];
                float wsel = kq ? whi : wlo;
                rgbA0 = fmaf(wsel, r0, rgbA0);
                rgbA1 = fmaf(wsel, r1, rgbA1);
                rgbA2 = fmaf(wsel, r2, rgbA2);
                if (l < 16) {
                    int base = O_RGB + (slot * PP + p) * 3;
                    out[base + 0] = r0; out[base + 1] = r1; out[base + 2] = r2;
                }
            }
        }
    }
    if (l < 16) {
        out[p * 3 + 0] = rgbA0;
        out[p * 3 + 1] = rgbA1;
        out[p * 3 + 2] = rgbA2;
    }
}

extern "C" void kernel_launch(void* const* d_in, const int* in_sizes, int n_in,
                              void* d_out, int out_size, void* d_ws, size_t ws_size,
                              hipStream_t stream) {
    const float* coor  = (const float*)d_in[0];
    const float* view  = (const float*)d_in[1];
    const float* slots = (const float*)d_in[2];
    const float* dens  = (const float*)d_in[3];
    const float* shf   = (const float*)d_in[4];
    const float* Wb0 = (const float*)d_in[5];  const float* bb0 = (const float*)d_in[6];
    const float* Wb1 = (const float*)d_in[7];  const float* bb1 = (const float*)d_in[8];
    const float* Wb2 = (const float*)d_in[9];  const float* bb2 = (const float*)d_in[10];
    const float* Wa0 = (const float*)d_in[11]; const float* ba0 = (const float*)d_in[12];
    const float* Wa1 = (const float*)d_in[13]; const float* ba1 = (const float*)d_in[14];
    const float* Wa2 = (const float*)d_in[15]; const float* ba2 = (const float*)d_in[16];
    const float* Wl  = (const float*)d_in[17]; const float* bl  = (const float*)d_in[18];
    const float* Wv  = (const float*)d_in[19]; const float* bv  = (const float*)d_in[20];
    const float* Wc0 = (const float*)d_in[21]; const float* bc0 = (const float*)d_in[22];
    const float* Wc1 = (const float*)d_in[23]; const float* bc1 = (const float*)d_in[24];
    const int*   ray = (const int*)d_in[25];
    float* out = (float*)d_out;

    prep_kernel<<<dim3(1), dim3(256), 0, stream>>>(
        slots, Wb0, bb0, Wb1, bb1, Wb2, bb2,
        Wa0, ba0, Wa1, ba1, Wa2, ba2,
        Wl, bl, Wv, bv, Wc0, bc0, Wc1, bc1, (char*)d_ws);

    decoder_kernel<<<dim3(PP / 64), dim3(256), 0, stream>>>(
        coor, view, dens, shf, ray, (const char*)d_ws, out);
}